// Round 8
// baseline (236.416 us; speedup 1.0000x reference)
//
#include <hip/hip_runtime.h>

// Block-diagonal linear: y[b, n*64+d] = sum_s x[b, n*64+s] * W[n][d][s]
// B = 8192, 64 blocks of 64x64. fp32 in/out, bf16 MFMA internally.
//
// Round-8: barrier-free wave-autonomous streaming.
//  - Each WAVE independently processes items of (16 rows x 4 n-blocks):
//    load 16x 1-KB rows -> wave-private LDS (bf16) -> MFMA (all 64 d per
//    block) -> y transposed through the SAME 8-KB LDS buffer (bf16 stage)
//    -> 16x 1-KB contiguous row stores. Zero __syncthreads in the loop;
//    within-wave DS ordering suffices.
//  - W (4 blocks, bf16, swizzled) staged once per WG into shared LDS
//    (read-only after the single startup barrier); frags re-read per item.
//  - 2048 independent wave-streams -> continuous memory issue (the fill
//    evidence: 6.6 TB/s needs continuity, not occupancy or burst length).

#define INF 4096
#define NROWS 8192

typedef short bf16x8 __attribute__((ext_vector_type(8)));
typedef short bf16x4 __attribute__((ext_vector_type(4)));
typedef float f32x4 __attribute__((ext_vector_type(4)));

__device__ inline unsigned short bf_rne(float f) {
    union { float f; unsigned u; } v; v.f = f;
    unsigned u = v.u;
    u += 0x7fffu + ((u >> 16) & 1u);
    return (unsigned short)(u >> 16);
}

__device__ inline bf16x4 cvt4(float4 a) {
    bf16x4 r;
    r[0] = (short)bf_rne(a.x); r[1] = (short)bf_rne(a.y);
    r[2] = (short)bf_rne(a.z); r[3] = (short)bf_rne(a.w);
    return r;
}

__device__ inline bf16x4 cvt4v(f32x4 a) {
    bf16x4 r;
    r[0] = (short)bf_rne(a[0]); r[1] = (short)bf_rne(a[1]);
    r[2] = (short)bf_rne(a[2]); r[3] = (short)bf_rne(a[3]);
    return r;
}

__device__ inline bf16x8 cvt8(float4 a, float4 b) {
    bf16x8 r;
    r[0] = (short)bf_rne(a.x); r[1] = (short)bf_rne(a.y);
    r[2] = (short)bf_rne(a.z); r[3] = (short)bf_rne(a.w);
    r[4] = (short)bf_rne(b.x); r[5] = (short)bf_rne(b.y);
    r[6] = (short)bf_rne(b.z); r[7] = (short)bf_rne(b.w);
    return r;
}

__device__ inline float up(short s) {
    union { unsigned u; float f; } v;
    v.u = ((unsigned)(unsigned short)s) << 16;
    return v.f;
}

// x/y stage: [16][256] bf16, 512-B rows.  W tile: [64][64] bf16, 128-B rows.
// XOR of row bits into byte bits 4..6 permutes 16-B slots (conflict-free, r4/r7).
__device__ inline int swzx(int row, int cb) { return row * 512 + (cb ^ ((row & 7) << 4)); }
__device__ inline int swzw(int row, int cb) { return row * 128 + (cb ^ ((row & 7) << 4)); }

__global__ __launch_bounds__(256, 2) void StructuredLinearBlocks_kernel(
        const float* __restrict__ x, const float* __restrict__ w,
        float* __restrict__ y) {
    __shared__ alignas(16) char lds[65536];
    // [0, 32K): W bf16, 4 blocks x 8 KB (swizzled).  [32K + wid*8K): wave stage.

    const int tid  = threadIdx.x;
    const int wid  = tid >> 6;
    const int lane = tid & 63;
    const int l15  = lane & 15;
    const int lhi  = lane >> 4;

    const int bid    = blockIdx.x;
    const int g      = bid & 15;            // n-group (4 blocks)
    const int sgrp   = bid >> 4;            // 0..31
    const int stream = sgrp * 4 + wid;      // 0..127 within group
    const int c0     = g * 256;             // f32 column base

    // ---- Stage W once: 4 blocks x 16 KB f32 -> bf16 LDS (swizzled). ----
    {
        const int d  = tid >> 2;            // 0..63
        const int kq = (tid & 3) * 16;      // f32 k base (16 f32 per thread)
#pragma unroll
        for (int n = 0; n < 4; ++n) {
            const float* p = w + (size_t)(g * 4 + n) * 4096 + d * 64 + kq;
            float4 p0 = *(const float4*)p;
            float4 p1 = *(const float4*)(p + 4);
            float4 p2 = *(const float4*)(p + 8);
            float4 p3 = *(const float4*)(p + 12);
            *(bf16x8*)(lds + n * 8192 + swzw(d, kq * 2))      = cvt8(p0, p1);
            *(bf16x8*)(lds + n * 8192 + swzw(d, kq * 2 + 16)) = cvt8(p2, p3);
        }
    }
    __syncthreads();   // the ONLY barrier

    char* xs = lds + 32768 + wid * 8192;   // wave-private x-tile / y-stage

    // ---- Prefetch item 0 (16 rows x 1-KB contiguous insts). ----
    float4 xv[16];
    {
        const size_t row0 = (size_t)stream * 16;
#pragma unroll
        for (int r = 0; r < 16; ++r)
            xv[r] = *(const float4*)(x + (row0 + r) * INF + c0 + lane * 4);
    }

#pragma unroll 1
    for (int it = 0; it < 4; ++it) {
        const size_t row0 = (size_t)it * 2048 + (size_t)stream * 16;

        // 1. Stage x tile (bf16, swizzled).
#pragma unroll
        for (int r = 0; r < 16; ++r)
            *(bf16x4*)(xs + swzx(r, lane * 8)) = cvt4(xv[r]);

        // 2. Read ALL x frags up front (frees the buffer for the y stage).
        //    lane = x[l15][n*64 + h*32 + lhi*8 ..+7]
        bf16x8 xf[4][2];
#pragma unroll
        for (int n = 0; n < 4; ++n)
#pragma unroll
            for (int h = 0; h < 2; ++h)
                xf[n][h] = *(const bf16x8*)(xs + swzx(l15, n * 128 + h * 64 + lhi * 16));

        // 3. Per n-block: W frags from shared LDS, 8 MFMA, acc -> y stage (bf16).
#pragma unroll
        for (int n = 0; n < 4; ++n) {
#pragma unroll
            for (int dt = 0; dt < 4; ++dt) {
                bf16x8 wf0 = *(const bf16x8*)(lds + n * 8192 + swzw(dt * 16 + l15, lhi * 16));
                bf16x8 wf1 = *(const bf16x8*)(lds + n * 8192 + swzw(dt * 16 + l15, 64 + lhi * 16));
                f32x4 a = (f32x4){0.f, 0.f, 0.f, 0.f};
                a = __builtin_amdgcn_mfma_f32_16x16x32_bf16(wf0, xf[n][0], a, 0, 0, 0);
                a = __builtin_amdgcn_mfma_f32_16x16x32_bf16(wf1, xf[n][1], a, 0, 0, 0);
                // D: col(l15)=b-row, row(lhi*4+j)=d  -> y[l15][n*64+dt*16+lhi*4+j]
                *(bf16x4*)(xs + swzx(l15, n * 128 + dt * 32 + lhi * 8)) = cvt4v(a);
            }
        }

        // 4. Prefetch next item's rows (issued before the store phase).
        if (it < 3) {
            const size_t nrow0 = (size_t)(it + 1) * 2048 + (size_t)stream * 16;
#pragma unroll
            for (int r = 0; r < 16; ++r)
                xv[r] = *(const float4*)(x + (nrow0 + r) * INF + c0 + lane * 4);
        }

        // 5. y-stage readback + 1-KB contiguous row stores.
#pragma unroll
        for (int r = 0; r < 16; ++r) {
            bf16x4 v = *(const bf16x4*)(xs + swzx(r, lane * 8));
            float4 o = make_float4(up(v[0]), up(v[1]), up(v[2]), up(v[3]));
            *(float4*)(y + (row0 + r) * INF + c0 + lane * 4) = o;
        }
    }
}

extern "C" void kernel_launch(void* const* d_in, const int* in_sizes, int n_in,
                              void* d_out, int out_size, void* d_ws, size_t ws_size,
                              hipStream_t stream) {
    const float* x = (const float*)d_in[0];   // [8192, 4096] fp32
    const float* w = (const float*)d_in[1];   // [64, 64, 64] fp32
    float* y = (float*)d_out;                 // [8192, 4096] fp32

    dim3 grid(512);    // 16 n-groups x 32 stream-groups; 2 WGs/CU, all resident
    dim3 block(256);
    StructuredLinearBlocks_kernel<<<grid, block, 0, stream>>>(x, w, y);
}